// Round 8
// baseline (537.744 us; speedup 1.0000x reference)
//
#include <hip/hip_runtime.h>
#include <stdint.h>

typedef __attribute__((ext_vector_type(8))) __bf16 bf16x8;
typedef __attribute__((ext_vector_type(4))) float f32x4;
typedef __attribute__((ext_vector_type(16))) float f32x16;
typedef unsigned short u16;
typedef unsigned char u8;
typedef unsigned int u32;
typedef unsigned long long u64;
typedef long i64;

#define LN_EPS 1e-5f

__device__ __forceinline__ float bf2f(u16 u){
  union { u32 i; float f; } v; v.i = ((u32)u) << 16; return v.f;
}
__device__ __forceinline__ u16 f2bf(float f){
  union { float f; u32 i; } v; v.f = f;
  u32 u = v.i;
  u += 0x7fffu + ((u >> 16) & 1u);
  return (u16)(u >> 16);
}
// HW packed f32x2 -> 2x OCP e4m3 bytes (low word of dst). RNE + sat@448.
__device__ __forceinline__ u32 cvt_pk_fp8(float a, float b){
  u32 pk;
  asm("v_cvt_pk_fp8_f32 %0, %1, %2" : "=v"(pk) : "v"(a), "v"(b));
  return pk;   // byte0 = fp8(a), byte1 = fp8(b)
}

// Async global->LDS DMA, 16 B per lane (dest = uniform base + lane*16).
__device__ __forceinline__ void gload_lds16(const void* g, void* l) {
  __builtin_amdgcn_global_load_lds(
      (const __attribute__((address_space(1))) void*)g,
      (__attribute__((address_space(3))) void*)l, 16, 0, 0);
}

// ---------------------------------------------------------------------------
// Kernel 0 (merged): blocks 0..4095 cast X f32->bf16; blocks 4096..4287
// transpose the three 512x512 weight matrices via 64x64 LDS tiles
// (coalesced read AND write; old version had 16x read amplification).
// ---------------------------------------------------------------------------
__global__ void prep_kernel(const float* __restrict__ X, u16* __restrict__ Xb,
                            const float* __restrict__ Wq,
                            const float* __restrict__ Wk,
                            const float* __restrict__ Wv,
                            u16* __restrict__ Wt) {
  __shared__ float Ts[64 * 65];   // stride 65 dwords: conflict-free both ways
  const int tid = threadIdx.x;
  const int bid = blockIdx.x;
  if (bid < 4096) {
    int idx = (bid * 256 + tid) * 8;
    float4 f0 = *(const float4*)&X[idx];
    float4 f1 = *(const float4*)&X[idx + 4];
    ushort4 lo, hi;
    lo.x = f2bf(f0.x); lo.y = f2bf(f0.y); lo.z = f2bf(f0.z); lo.w = f2bf(f0.w);
    hi.x = f2bf(f1.x); hi.y = f2bf(f1.y); hi.z = f2bf(f1.z); hi.w = f2bf(f1.w);
    *(ushort4*)&Xb[idx] = lo;
    *(ushort4*)&Xb[idx + 4] = hi;
    return;
  }
  const int t = bid - 4096;            // 0..191
  const int m = t >> 6;                // matrix index
  const int tt = t & 63;               // 8x8 grid of 64x64 tiles
  const int d0 = (tt >> 3) * 64, e0 = (tt & 7) * 64;
  const float* W = (m == 0) ? Wq : ((m == 1) ? Wk : Wv);
  u16* o = Wt + m * 512 * 512;

  const int r4 = tid >> 6;             // wave id: 4 rows per pass
  const int c = tid & 63;
#pragma unroll
  for (int rr = 0; rr < 16; rr++) {
    int r = rr * 4 + r4;
    Ts[c * 65 + r] = W[(d0 + r) * 512 + e0 + c];   // coalesced read
  }
  __syncthreads();
  // out: Wt[e][d].  512 tasks (64 e-rows x 8 16B segs) over 256 threads.
#pragma unroll
  for (int it = 0; it < 2; it++) {
    int task = it * 256 + tid;
    int e = task >> 3;
    int seg = task & 7;
    const float* src = &Ts[e * 65 + seg * 8];
    union { u16 h[8]; uint4 v; } pk;
#pragma unroll
    for (int j = 0; j < 8; j++) pk.h[j] = f2bf(src[j]);
    *(uint4*)&o[(e0 + e) * 512 + d0 + seg * 8] = pk.v;   // coalesced write
  }
}

// ---------------------------------------------------------------------------
// Kernel 2: QKV GEMM, fully DMA-staged (global_load_lds w=16 for A and B).
// As/Bs: 128 rows x 64 B, 16B granule g of row r stored at position g^(r&3).
// Q,K out fp8 [tok][e]; V out fp8 TRANSPOSED Vt8[512][16384].
// r8: Q/K use SWAPPED MFMA operands (C row<->col exchange) so acc regs walk
// the e dimension -> u32 packs into Ls[tok][e], then coalesced 16B stores.
// (old path: byte stores, ~4x write amplification).  V path unchanged (r6).
// ---------------------------------------------------------------------------
__launch_bounds__(256, 4)
__global__ void qkv_gemm_kernel(const u16* __restrict__ Xb,
                                const u16* __restrict__ Wt,
                                u8* __restrict__ Qo,
                                u8* __restrict__ Ko,
                                u8* __restrict__ Vto8) {
  const int z = blockIdx.y;
  const u16* Wtm = Wt + z * 512 * 512;
  const int mblk = blockIdx.x & 127;
  const int nblk = blockIdx.x >> 7;
  const int m0 = mblk * 128, n0 = nblk * 128;

  __shared__ __align__(16) u8 As[128 * 64];   // 8 KB
  __shared__ __align__(16) u8 Bs[128 * 64];   // 8 KB
  __shared__ __align__(16) u8 Ls[128 * 144];  // 18 KB, epilogue transpose

  const int tid = threadIdx.x;
  const int lane = tid & 63, w = tid >> 6;
  const int wr = w >> 1, wc = w & 1;
  const int lrow = lane & 15, quad = lane >> 4;
  const bool swp = (z < 2);

  f32x4 acc[4][4];
#pragma unroll
  for (int i = 0; i < 4; i++)
#pragma unroll
    for (int j = 0; j < 4; j++) acc[i][j] = (f32x4){0.f, 0.f, 0.f, 0.f};

  const int srow = lane >> 2;          // 0..15 within run
  const int spos = lane & 3;           // granule position 0..3

  // preload k0 = 0
#pragma unroll
  for (int r2 = 0; r2 < 2; r2++) {
    int rowb = w * 32 + r2 * 16;
    int row = rowb + srow;
    int g = spos ^ (row & 3);
    gload_lds16(&Xb[(m0 + row) * 512 + g * 8], &As[rowb * 64]);
    gload_lds16(&Wtm[(n0 + row) * 512 + g * 8], &Bs[rowb * 64]);
  }

  for (int k = 0; k < 16; k++) {
    __syncthreads();   // tile-k DMAs complete (implicit vmcnt(0))
    bf16x8 a[4], b[4];
#pragma unroll
    for (int t = 0; t < 4; t++) {
      int ra = wr * 64 + t * 16 + lrow;
      a[t] = *(const bf16x8*)&As[ra * 64 + (quad ^ (ra & 3)) * 16];
      int rb = wc * 64 + t * 16 + lrow;
      b[t] = *(const bf16x8*)&Bs[rb * 64 + (quad ^ (rb & 3)) * 16];
    }
    __syncthreads();   // all waves' fragment reads done -> safe to restage
    if (k < 15) {
      int k0n = (k + 1) * 32;
#pragma unroll
      for (int r2 = 0; r2 < 2; r2++) {
        int rowb = w * 32 + r2 * 16;
        int row = rowb + srow;
        int g = spos ^ (row & 3);
        gload_lds16(&Xb[(m0 + row) * 512 + k0n + g * 8], &As[rowb * 64]);
        gload_lds16(&Wtm[(n0 + row) * 512 + k0n + g * 8], &Bs[rowb * 64]);
      }
    }
    if (swp) {   // Q/K: C[row=e][col=tok] -> acc regs walk e (uniform branch)
#pragma unroll
      for (int i = 0; i < 4; i++)
#pragma unroll
        for (int j = 0; j < 4; j++)
          acc[i][j] = __builtin_amdgcn_mfma_f32_16x16x32_bf16(b[j], a[i], acc[i][j], 0, 0, 0);
    } else {     // V: C[row=tok][col=e]
#pragma unroll
      for (int i = 0; i < 4; i++)
#pragma unroll
        for (int j = 0; j < 4; j++)
          acc[i][j] = __builtin_amdgcn_mfma_f32_16x16x32_bf16(a[i], b[j], acc[i][j], 0, 0, 0);
    }
  }

  if (swp) {
    // acc[i][j][r]: e = wc*64+j*16+quad*4+r, tok = wr*64+i*16+lrow.
    u8* O = (z == 0) ? Qo : Ko;
#pragma unroll
    for (int i = 0; i < 4; i++) {
      int tok = wr * 64 + i * 16 + lrow;
#pragma unroll
      for (int j = 0; j < 4; j++) {
        int eb = wc * 64 + j * 16 + quad * 4;
        u32 pk01 = cvt_pk_fp8(acc[i][j][0], acc[i][j][1]);
        u32 pk23 = cvt_pk_fp8(acc[i][j][2], acc[i][j][3]);
        u32 pk = (pk01 & 0xffffu) | (pk23 << 16);
        *(u32*)&Ls[tok * 144 + eb] = pk;   // 2-way banked, free
      }
    }
    __syncthreads();
#pragma unroll
    for (int kk = 0; kk < 4; kk++) {
      int tok = w * 32 + kk * 8 + (lane >> 3);
      int e = (lane & 7) * 16;
      uint4 vv = *(const uint4*)&Ls[tok * 144 + e];
      *(uint4*)&O[(size_t)(m0 + tok) * 512 + n0 + e];
      *(uint4*)&O[(size_t)(m0 + tok) * 512 + n0 + e] = vv;
    }
  } else {
    // ---- V: LDS transpose tile, then coalesced row stores (r6 path) ----
#pragma unroll
    for (int i = 0; i < 4; i++) {
      int tokb = wr * 64 + i * 16 + quad * 4;
#pragma unroll
      for (int j = 0; j < 4; j++) {
        int el = wc * 64 + j * 16 + lrow;
        u32 pk01 = cvt_pk_fp8(acc[i][j][0], acc[i][j][1]);
        u32 pk23 = cvt_pk_fp8(acc[i][j][2], acc[i][j][3]);
        u32 pk = (pk01 & 0xffffu) | (pk23 << 16);
        *(u32*)&Ls[el * 144 + tokb] = pk;
      }
    }
    __syncthreads();
#pragma unroll
    for (int k = 0; k < 4; k++) {
      int e = w * 32 + k * 8 + (lane >> 3);
      int tok = (lane & 7) * 16;
      uint4 vv = *(const uint4*)&Ls[e * 144 + tok];
      *(uint4*)&Vto8[(size_t)(n0 + e) * 16384 + m0 + tok] = vv;
    }
  }
}

// ---------------------------------------------------------------------------
// Kernel 3: flash attention partial, all-fp8 MFMA paths.
// r6 schedule (measured 148 us; KVBLK=32, single-buffer, 2 barriers/tile).
// r8: + s_setprio(1/0) around both MFMA clusters (T5; m191-validated in
// exactly this regime: 2 blocks/CU at uncorrelated phases).  Only change.
// ---------------------------------------------------------------------------
template <int NSPLIT>
__launch_bounds__(256, 2)
__global__ void attn_partial_kernel(const u8* __restrict__ Q,
                                    const u8* __restrict__ K,
                                    const u8* __restrict__ Vt8,
                                    u16* __restrict__ Opart,  // [NSPLIT][16384][512]
                                    float* __restrict__ L) {  // [NSPLIT][16384]
  constexpr int SPAN = 4096 / NSPLIT;   // keys per split
  constexpr int ITERS = SPAN / 32;      // 32-key tiles
  const int b = blockIdx.y;
  const int split = blockIdx.z;
  const int q0 = blockIdx.x * 64;
  const int tid = threadIdx.x;
  const int lane = tid & 63, w = tid >> 6;
  const int lrow = lane & 15, quad = lane >> 4;
  const int l31 = lane & 31, half = lane >> 5;

  __shared__ __align__(16) u8 Ks8[32 * 512];   // fp8, 16B-granule swizzle g^(row&7)
  __shared__ __align__(16) u8 Vs8[512 * 32];   // fp8, granule g16^((n>>2)&1)
  __shared__ __align__(16) u8 Pb8[64 * 40];    // fp8 P, row stride 40 B

  const int keybase = b * 4096 + split * SPAN;

  const int qtok = b * 4096 + q0 + w * 16 + lrow;
  i64 qf[16];
#pragma unroll
  for (int s = 0; s < 16; s++)
    qf[s] = *(const i64*)&Q[qtok * 512 + s * 32 + quad * 8];

  f32x16 Oacc[2][4];
#pragma unroll
  for (int i = 0; i < 2; i++)
#pragma unroll
    for (int j = 0; j < 4; j++)
#pragma unroll
      for (int e = 0; e < 16; e++) Oacc[i][j][e] = 0.f;

  float lsum[4] = {0.f, 0.f, 0.f, 0.f};
  const float scale = 0.044194173824159216f;  // 1/sqrt(512)

  // ---- preload tile 0 ----
#pragma unroll
  for (int i = 0; i < 4; i++) {       // K fp8: 8 rows/wave, 2 rows per run
    int row = w * 8 + i * 2 + (lane >> 5);
    int g = (lane & 31) ^ (row & 7);
    gload_lds16(&K[(keybase + row) * 512 + g * 16], &Ks8[(w * 8 + i * 2) * 512]);
  }
#pragma unroll
  for (int run = 0; run < 4; run++) { // V fp8: wave-private 128 rows, 32/run
    int rowb = w * 128 + run * 32;
    int n = rowb + (lane >> 1);
    int g16 = (lane & 1) ^ ((n >> 2) & 1);
    gload_lds16(&Vt8[n * 16384 + keybase + g16 * 16], &Vs8[rowb * 32]);
  }

  for (int it = 0; it < ITERS; ++it) {
    __syncthreads();  // tile-it DMAs done (implicit vmcnt(0)); Pb8(it-1) free

    // ---- QK^T (fp8) : S[16 rows][32 keys] per wave ----
    f32x4 S0 = {0.f, 0.f, 0.f, 0.f}, S1 = {0.f, 0.f, 0.f, 0.f};
    __builtin_amdgcn_s_setprio(1);
#pragma unroll
    for (int s = 0; s < 16; s++) {
      int gs = (2 * s + (quad >> 1)) ^ (lrow & 7);
      int off = gs * 16 + (quad & 1) * 8;
      i64 k0 = *(const i64*)&Ks8[lrow * 512 + off];
      i64 k1 = *(const i64*)&Ks8[(16 + lrow) * 512 + off];
      S0 = __builtin_amdgcn_mfma_f32_16x16x32_fp8_fp8(qf[s], k0, S0, 0, 0, 0);
      S1 = __builtin_amdgcn_mfma_f32_16x16x32_fp8_fp8(qf[s], k1, S1, 0, 0, 0);
    }
    __builtin_amdgcn_s_setprio(0);

    // ---- fixed-max softmax + write P as fp8 (HW packed convert) ----
#pragma unroll
    for (int r = 0; r < 4; r++) {
      float p0 = __expf(S0[r] * scale);
      float p1 = __expf(S1[r] * scale);
      lsum[r] += p0 + p1;
      u32 pk = cvt_pk_fp8(p0, p1);
      int prow = w * 16 + quad * 4 + r;
      Pb8[prow * 40 + lrow] = (u8)pk;
      Pb8[prow * 40 + 16 + lrow] = (u8)(pk >> 8);
    }

    __syncthreads();  // P visible; Ks fully consumed

    const int kknext = (it + 1) * 32;
    if (it < ITERS - 1) {    // prefetch K(it+1), flies during PV
#pragma unroll
      for (int i = 0; i < 4; i++) {
        int row = w * 8 + i * 2 + (lane >> 5);
        int g = (lane & 31) ^ (row & 7);
        gload_lds16(&K[(keybase + kknext + row) * 512 + g * 16],
                    &Ks8[(w * 8 + i * 2) * 512]);
      }
    }

    // ---- PV (fp8): hoist all fragment reads, drain, prefetch V, MFMA ----
    i64 af[2][2];
#pragma unroll
    for (int i = 0; i < 2; i++)
#pragma unroll
      for (int kg = 0; kg < 2; kg++)
        af[i][kg] = *(const i64*)&Pb8[(i * 32 + l31) * 40 + kg * 16 + half * 8];

    i64 bv[4][2];
#pragma unroll
    for (int j = 0; j < 4; j++) {
      int n = w * 128 + j * 32 + l31;
      int x = (n >> 2) & 1;
#pragma unroll
      for (int kg = 0; kg < 2; kg++)
        bv[j][kg] = *(const i64*)&Vs8[n * 32 + (kg ^ x) * 16 + half * 8];
    }

    asm volatile("s_waitcnt lgkmcnt(0)" ::: "memory");

    if (it < ITERS - 1) {    // prefetch V(it+1), wave-private slice
#pragma unroll
      for (int run = 0; run < 4; run++) {
        int rowb = w * 128 + run * 32;
        int n = rowb + (lane >> 1);
        int g16 = (lane & 1) ^ ((n >> 2) & 1);
        gload_lds16(&Vt8[n * 16384 + keybase + kknext + g16 * 16], &Vs8[rowb * 32]);
      }
    }

    __builtin_amdgcn_s_setprio(1);
#pragma unroll
    for (int j = 0; j < 4; j++)
#pragma unroll
      for (int i = 0; i < 2; i++) {
        Oacc[i][j] = __builtin_amdgcn_mfma_f32_32x32x16_fp8_fp8(af[i][0], bv[j][0], Oacc[i][j], 0, 0, 0);
        Oacc[i][j] = __builtin_amdgcn_mfma_f32_32x32x16_fp8_fp8(af[i][1], bv[j][1], Oacc[i][j], 0, 0, 0);
      }
    __builtin_amdgcn_s_setprio(0);
  }

  // ---- reduce l across the 16 key-lanes ----
#pragma unroll
  for (int r = 0; r < 4; r++) {
    float s = lsum[r];
    s += __shfl_xor(s, 1); s += __shfl_xor(s, 2);
    s += __shfl_xor(s, 4); s += __shfl_xor(s, 8);
    lsum[r] = s;
  }
  const int tokw = b * 4096 + q0 + w * 16 + quad * 4;
  if (lrow == 0) {
#pragma unroll
    for (int r = 0; r < 4; r++)
      L[split * 16384 + tokw + r] = lsum[r];
  }

  // ---- store unnormalized O partial, bf16 (32x32 C-layout) ----
  u16* Ob = Opart + (size_t)split * (16384u * 512u);
  const int tokbase = b * 4096 + q0;
#pragma unroll
  for (int i = 0; i < 2; i++)
#pragma unroll
    for (int j = 0; j < 4; j++) {
      int col = w * 128 + j * 32 + l31;
#pragma unroll
      for (int p = 0; p < 16; p++) {
        int row = i * 32 + (p & 3) + 8 * (p >> 2) + 4 * half;
        Ob[(tokbase + row) * 512 + col] = f2bf(Oacc[i][j][p]);
      }
    }
}

// ---------------------------------------------------------------------------
// Kernel 4: combine splits + residual + LayerNorm.  One wave per token.
// ---------------------------------------------------------------------------
template <int NSPLIT>
__launch_bounds__(256)
__global__ void combine_ln_kernel(const u16* __restrict__ Opart,
                                  const float* __restrict__ L,
                                  const float* __restrict__ X,
                                  const float* __restrict__ gamma,
                                  const float* __restrict__ beta,
                                  float* __restrict__ Out) {
  const int lane = threadIdx.x & 63;
  const int tok = blockIdx.x * 4 + (threadIdx.x >> 6);
  float lt = 0.f;
#pragma unroll
  for (int s = 0; s < NSPLIT; s++) lt += L[s * 16384 + tok];
  const float inv_l = 1.f / lt;
  const int base = tok * 512 + lane * 8;

  float h[8] = {0.f, 0.f, 0.f, 0.f, 0.f, 0.f, 0.f, 0.f};
#pragma unroll
  for (int s = 0; s < NSPLIT; s++) {
    uint4 avec = *(const uint4*)&Opart[(size_t)s * (16384u * 512u) + base];
    const u16* ap = (const u16*)&avec;
#pragma unroll
    for (int i = 0; i < 8; i++) h[i] += bf2f(ap[i]);
  }

  float4 x0 = *(const float4*)&X[base];
  float4 x1 = *(const float4*)&X[base + 4];
  float xs[8] = {x0.x, x0.y, x0.z, x0.w, x1.x, x1.y, x1.z, x1.w};
#pragma unroll
  for (int i = 0; i < 8; i++) h[i] = h[i] * inv_l + xs[i];

  float sum = 0.f, sq = 0.f;
#pragma unroll
  for (int i = 0; i < 8; i++) { sum += h[i]; sq += h[i] * h[i]; }
#pragma unroll
  for (int d = 1; d < 64; d <<= 1) {
    sum += __shfl_xor(sum, d);
    sq  += __shfl_xor(sq, d);
  }
  float mu = sum * (1.f / 512.f);
  float var = sq * (1.f / 512.f) - mu * mu;
  float rstd = rsqrtf(var + LN_EPS);

  float4 g0 = *(const float4*)&gamma[lane * 8];
  float4 g1 = *(const float4*)&gamma[lane * 8 + 4];
  float4 b0 = *(const float4*)&beta[lane * 8];
  float4 b1 = *(const float4*)&beta[lane * 8 + 4];
  float gs[8] = {g0.x, g0.y, g0.z, g0.w, g1.x, g1.y, g1.z, g1.w};
  float bs[8] = {b0.x, b0.y, b0.z, b0.w, b1.x, b1.y, b1.z, b1.w};

  float4 o0, o1;
  float* op = (float*)&o0;
#pragma unroll
  for (int i = 0; i < 4; i++) op[i] = (h[i] - mu) * rstd * gs[i] + bs[i];
  float* op1 = (float*)&o1;
#pragma unroll
  for (int i = 0; i < 4; i++) op1[i] = (h[i + 4] - mu) * rstd * gs[i + 4] + bs[i + 4];
  *(float4*)&Out[base] = o0;
  *(float4*)&Out[base + 4] = o1;
}

// ---------------------------------------------------------------------------
extern "C" void kernel_launch(void* const* d_in, const int* in_sizes, int n_in,
                              void* d_out, int out_size, void* d_ws, size_t ws_size,
                              hipStream_t stream) {
  const float* x = (const float*)d_in[0];
  const float* Wq = (const float*)d_in[1];
  const float* Wk = (const float*)d_in[2];
  const float* Wv = (const float*)d_in[3];
  const float* gamma = (const float*)d_in[4];
  const float* beta = (const float*)d_in[5];

  char* ws = (char*)d_ws;
  u8*  Qws   = (u8*)(ws);                     // 8 MB fp8
  u8*  Kws   = (u8*)(ws + 8388608);           // 8 MB fp8
  u8*  Vt8ws = (u8*)(ws + 16777216);          // 8 MB fp8, [512][16384]
  u16* Wtws  = (u16*)(ws + 25165824);         // 1.5 MB bf16
  u16* Xbws  = (u16*)(ws + 26738688);         // 16 MB bf16 (dead after GEMM)
  u16* Opws  = (u16*)(ws + 26738688);         // 2 x 16 MB bf16 partials;
                                              //   slice 0 aliases Xb (safe:
                                              //   attn writes after gemm reads)
  const size_t PART = 16777216;
  float* Lws = (float*)(ws + 26738688 + 2 * PART);  // [2][16384] f32

  hipLaunchKernelGGL(prep_kernel, dim3(4288), dim3(256), 0, stream,
                     x, Xbws, Wq, Wk, Wv, Wtws);
  hipLaunchKernelGGL(qkv_gemm_kernel, dim3(512, 3), dim3(256), 0, stream,
                     Xbws, Wtws, Qws, Kws, Vt8ws);
  hipLaunchKernelGGL(HIP_KERNEL_NAME(attn_partial_kernel<2>),
                     dim3(64, 4, 2), dim3(256), 0, stream,
                     Qws, Kws, Vt8ws, Opws, Lws);
  hipLaunchKernelGGL(HIP_KERNEL_NAME(combine_ln_kernel<2>),
                     dim3(4096), dim3(256), 0, stream,
                     Opws, Lws, x, gamma, beta, (float*)d_out);
}

// Round 10
// 271.195 us; speedup vs baseline: 1.9829x; 1.9829x over previous
//
#include <hip/hip_runtime.h>
#include <stdint.h>

typedef __attribute__((ext_vector_type(8))) __bf16 bf16x8;
typedef __attribute__((ext_vector_type(4))) float f32x4;
typedef __attribute__((ext_vector_type(16))) float f32x16;
typedef unsigned short u16;
typedef unsigned char u8;
typedef unsigned int u32;
typedef unsigned long long u64;
typedef long i64;

#define LN_EPS 1e-5f

__device__ __forceinline__ float bf2f(u16 u){
  union { u32 i; float f; } v; v.i = ((u32)u) << 16; return v.f;
}
__device__ __forceinline__ u16 f2bf(float f){
  union { float f; u32 i; } v; v.f = f;
  u32 u = v.i;
  u += 0x7fffu + ((u >> 16) & 1u);
  return (u16)(u >> 16);
}
// HW packed f32x2 -> 2x OCP e4m3 bytes (low word of dst). RNE + sat@448.
__device__ __forceinline__ u32 cvt_pk_fp8(float a, float b){
  u32 pk;
  asm("v_cvt_pk_fp8_f32 %0, %1, %2" : "=v"(pk) : "v"(a), "v"(b));
  return pk;   // byte0 = fp8(a), byte1 = fp8(b)
}

// Async global->LDS DMA, 16 B per lane (dest = uniform base + lane*16).
__device__ __forceinline__ void gload_lds16(const void* g, void* l) {
  __builtin_amdgcn_global_load_lds(
      (const __attribute__((address_space(1))) void*)g,
      (__attribute__((address_space(3))) void*)l, 16, 0, 0);
}

// ---------------------------------------------------------------------------
// Kernel 0 (merged): blocks 0..4095 cast X f32->bf16; blocks 4096..4287
// transpose the three 512x512 weight matrices via 64x64 LDS tiles.
// (r8-verified correct; fixes transpose_w's 16x read amplification.)
// ---------------------------------------------------------------------------
__global__ void prep_kernel(const float* __restrict__ X, u16* __restrict__ Xb,
                            const float* __restrict__ Wq,
                            const float* __restrict__ Wk,
                            const float* __restrict__ Wv,
                            u16* __restrict__ Wt) {
  __shared__ float Ts[64 * 65];   // stride 65 dwords: conflict-free both ways
  const int tid = threadIdx.x;
  const int bid = blockIdx.x;
  if (bid < 4096) {
    int idx = (bid * 256 + tid) * 8;
    float4 f0 = *(const float4*)&X[idx];
    float4 f1 = *(const float4*)&X[idx + 4];
    ushort4 lo, hi;
    lo.x = f2bf(f0.x); lo.y = f2bf(f0.y); lo.z = f2bf(f0.z); lo.w = f2bf(f0.w);
    hi.x = f2bf(f1.x); hi.y = f2bf(f1.y); hi.z = f2bf(f1.z); hi.w = f2bf(f1.w);
    *(ushort4*)&Xb[idx] = lo;
    *(ushort4*)&Xb[idx + 4] = hi;
    return;
  }
  const int t = bid - 4096;            // 0..191
  const int m = t >> 6;                // matrix index
  const int tt = t & 63;               // 8x8 grid of 64x64 tiles
  const int d0 = (tt >> 3) * 64, e0 = (tt & 7) * 64;
  const float* W = (m == 0) ? Wq : ((m == 1) ? Wk : Wv);
  u16* o = Wt + m * 512 * 512;

  const int r4 = tid >> 6;             // wave id: 4 rows per pass
  const int c = tid & 63;
#pragma unroll
  for (int rr = 0; rr < 16; rr++) {
    int r = rr * 4 + r4;
    Ts[c * 65 + r] = W[(d0 + r) * 512 + e0 + c];   // coalesced read
  }
  __syncthreads();
#pragma unroll
  for (int it = 0; it < 2; it++) {
    int task = it * 256 + tid;
    int e = task >> 3;
    int seg = task & 7;
    const float* src = &Ts[e * 65 + seg * 8];
    union { u16 h[8]; uint4 v; } pk;
#pragma unroll
    for (int j = 0; j < 8; j++) pk.h[j] = f2bf(src[j]);
    *(uint4*)&o[(e0 + e) * 512 + d0 + seg * 8] = pk.v;   // coalesced write
  }
}

// ---------------------------------------------------------------------------
// Kernel 2: QKV GEMM — EXACT r7 version (r9 lesson: the templated swapped-
// operand rewrite NaN'd despite passing inspection; r7's single-ordering
// kernel is harness-proven at r6/r7.  Q/K byte-store epilogue, V via LDS
// transpose tile + coalesced 16B row stores.)
// ---------------------------------------------------------------------------
__launch_bounds__(256, 4)
__global__ void qkv_gemm_kernel(const u16* __restrict__ Xb,
                                const u16* __restrict__ Wt,
                                u8* __restrict__ Qo,
                                u8* __restrict__ Ko,
                                u8* __restrict__ Vto8) {
  const int z = blockIdx.y;
  const u16* Wtm = Wt + z * 512 * 512;
  const int mblk = blockIdx.x & 127;
  const int nblk = blockIdx.x >> 7;
  const int m0 = mblk * 128, n0 = nblk * 128;

  __shared__ __align__(16) u8 As[128 * 64];   // 8 KB
  __shared__ __align__(16) u8 Bs[128 * 64];   // 8 KB
  __shared__ __align__(16) u8 Ls[128 * 144];  // 18 KB, V epilogue transpose

  const int tid = threadIdx.x;
  const int lane = tid & 63, w = tid >> 6;
  const int wr = w >> 1, wc = w & 1;
  const int lrow = lane & 15, quad = lane >> 4;

  f32x4 acc[4][4];
#pragma unroll
  for (int i = 0; i < 4; i++)
#pragma unroll
    for (int j = 0; j < 4; j++) acc[i][j] = (f32x4){0.f, 0.f, 0.f, 0.f};

  const int srow = lane >> 2;          // 0..15 within run
  const int spos = lane & 3;           // granule position 0..3

  // preload k0 = 0
#pragma unroll
  for (int r2 = 0; r2 < 2; r2++) {
    int rowb = w * 32 + r2 * 16;
    int row = rowb + srow;
    int g = spos ^ (row & 3);
    gload_lds16(&Xb[(m0 + row) * 512 + g * 8], &As[rowb * 64]);
    gload_lds16(&Wtm[(n0 + row) * 512 + g * 8], &Bs[rowb * 64]);
  }

  for (int k = 0; k < 16; k++) {
    __syncthreads();   // tile-k DMAs complete (implicit vmcnt(0))
    bf16x8 a[4], b[4];
#pragma unroll
    for (int t = 0; t < 4; t++) {
      int ra = wr * 64 + t * 16 + lrow;
      a[t] = *(const bf16x8*)&As[ra * 64 + (quad ^ (ra & 3)) * 16];
      int rb = wc * 64 + t * 16 + lrow;
      b[t] = *(const bf16x8*)&Bs[rb * 64 + (quad ^ (rb & 3)) * 16];
    }
    __syncthreads();   // all waves' fragment reads done -> safe to restage
    if (k < 15) {
      int k0n = (k + 1) * 32;
#pragma unroll
      for (int r2 = 0; r2 < 2; r2++) {
        int rowb = w * 32 + r2 * 16;
        int row = rowb + srow;
        int g = spos ^ (row & 3);
        gload_lds16(&Xb[(m0 + row) * 512 + k0n + g * 8], &As[rowb * 64]);
        gload_lds16(&Wtm[(n0 + row) * 512 + k0n + g * 8], &Bs[rowb * 64]);
      }
    }
#pragma unroll
    for (int i = 0; i < 4; i++)
#pragma unroll
      for (int j = 0; j < 4; j++)
        acc[i][j] = __builtin_amdgcn_mfma_f32_16x16x32_bf16(a[i], b[j], acc[i][j], 0, 0, 0);
  }

  if (z < 2) {
    u8* O = (z == 0) ? Qo : Ko;
#pragma unroll
    for (int i = 0; i < 4; i++) {
      int rbase = m0 + wr * 64 + i * 16 + quad * 4;
#pragma unroll
      for (int j = 0; j < 4; j++) {
        int col = n0 + wc * 64 + j * 16 + lrow;
        u32 pk01 = cvt_pk_fp8(acc[i][j][0], acc[i][j][1]);
        u32 pk23 = cvt_pk_fp8(acc[i][j][2], acc[i][j][3]);
        O[(rbase + 0) * 512 + col] = (u8)pk01;
        O[(rbase + 1) * 512 + col] = (u8)(pk01 >> 8);
        O[(rbase + 2) * 512 + col] = (u8)pk23;
        O[(rbase + 3) * 512 + col] = (u8)(pk23 >> 8);
      }
    }
  } else {
    // ---- V: LDS transpose tile, then coalesced row stores (r6 path) ----
#pragma unroll
    for (int i = 0; i < 4; i++) {
      int tokb = wr * 64 + i * 16 + quad * 4;
#pragma unroll
      for (int j = 0; j < 4; j++) {
        int el = wc * 64 + j * 16 + lrow;
        u32 pk01 = cvt_pk_fp8(acc[i][j][0], acc[i][j][1]);
        u32 pk23 = cvt_pk_fp8(acc[i][j][2], acc[i][j][3]);
        u32 pk = (pk01 & 0xffffu) | (pk23 << 16);
        *(u32*)&Ls[el * 144 + tokb] = pk;
      }
    }
    __syncthreads();
#pragma unroll
    for (int k = 0; k < 4; k++) {
      int e = w * 32 + k * 8 + (lane >> 3);
      int tok = (lane & 7) * 16;
      uint4 vv = *(const uint4*)&Ls[e * 144 + tok];
      *(uint4*)&Vto8[(size_t)(n0 + e) * 16384 + m0 + tok] = vv;
    }
  }
}

// ---------------------------------------------------------------------------
// Kernel 3: flash attention partial, all-fp8 MFMA paths.
// r6 schedule (measured 148 us) + s_setprio around MFMA clusters (T5,
// r8-verified correct).  This round finally yields a clean attn timing row:
// keep setprio if <= 151 us, drop otherwise.
// ---------------------------------------------------------------------------
template <int NSPLIT>
__launch_bounds__(256, 2)
__global__ void attn_partial_kernel(const u8* __restrict__ Q,
                                    const u8* __restrict__ K,
                                    const u8* __restrict__ Vt8,
                                    u16* __restrict__ Opart,  // [NSPLIT][16384][512]
                                    float* __restrict__ L) {  // [NSPLIT][16384]
  constexpr int SPAN = 4096 / NSPLIT;   // keys per split
  constexpr int ITERS = SPAN / 32;      // 32-key tiles
  const int b = blockIdx.y;
  const int split = blockIdx.z;
  const int q0 = blockIdx.x * 64;
  const int tid = threadIdx.x;
  const int lane = tid & 63, w = tid >> 6;
  const int lrow = lane & 15, quad = lane >> 4;
  const int l31 = lane & 31, half = lane >> 5;

  __shared__ __align__(16) u8 Ks8[32 * 512];   // fp8, 16B-granule swizzle g^(row&7)
  __shared__ __align__(16) u8 Vs8[512 * 32];   // fp8, granule g16^((n>>2)&1)
  __shared__ __align__(16) u8 Pb8[64 * 40];    // fp8 P, row stride 40 B

  const int keybase = b * 4096 + split * SPAN;

  const int qtok = b * 4096 + q0 + w * 16 + lrow;
  i64 qf[16];
#pragma unroll
  for (int s = 0; s < 16; s++)
    qf[s] = *(const i64*)&Q[qtok * 512 + s * 32 + quad * 8];

  f32x16 Oacc[2][4];
#pragma unroll
  for (int i = 0; i < 2; i++)
#pragma unroll
    for (int j = 0; j < 4; j++)
#pragma unroll
      for (int e = 0; e < 16; e++) Oacc[i][j][e] = 0.f;

  float lsum[4] = {0.f, 0.f, 0.f, 0.f};
  const float scale = 0.044194173824159216f;  // 1/sqrt(512)

  // ---- preload tile 0 ----
#pragma unroll
  for (int i = 0; i < 4; i++) {       // K fp8: 8 rows/wave, 2 rows per run
    int row = w * 8 + i * 2 + (lane >> 5);
    int g = (lane & 31) ^ (row & 7);
    gload_lds16(&K[(keybase + row) * 512 + g * 16], &Ks8[(w * 8 + i * 2) * 512]);
  }
#pragma unroll
  for (int run = 0; run < 4; run++) { // V fp8: wave-private 128 rows, 32/run
    int rowb = w * 128 + run * 32;
    int n = rowb + (lane >> 1);
    int g16 = (lane & 1) ^ ((n >> 2) & 1);
    gload_lds16(&Vt8[n * 16384 + keybase + g16 * 16], &Vs8[rowb * 32]);
  }

  for (int it = 0; it < ITERS; ++it) {
    __syncthreads();  // tile-it DMAs done (implicit vmcnt(0)); Pb8(it-1) free

    // ---- QK^T (fp8) : S[16 rows][32 keys] per wave ----
    f32x4 S0 = {0.f, 0.f, 0.f, 0.f}, S1 = {0.f, 0.f, 0.f, 0.f};
    __builtin_amdgcn_s_setprio(1);
#pragma unroll
    for (int s = 0; s < 16; s++) {
      int gs = (2 * s + (quad >> 1)) ^ (lrow & 7);
      int off = gs * 16 + (quad & 1) * 8;
      i64 k0 = *(const i64*)&Ks8[lrow * 512 + off];
      i64 k1 = *(const i64*)&Ks8[(16 + lrow) * 512 + off];
      S0 = __builtin_amdgcn_mfma_f32_16x16x32_fp8_fp8(qf[s], k0, S0, 0, 0, 0);
      S1 = __builtin_amdgcn_mfma_f32_16x16x32_fp8_fp8(qf[s], k1, S1, 0, 0, 0);
    }
    __builtin_amdgcn_s_setprio(0);

    // ---- fixed-max softmax + write P as fp8 (HW packed convert) ----
#pragma unroll
    for (int r = 0; r < 4; r++) {
      float p0 = __expf(S0[r] * scale);
      float p1 = __expf(S1[r] * scale);
      lsum[r] += p0 + p1;
      u32 pk = cvt_pk_fp8(p0, p1);
      int prow = w * 16 + quad * 4 + r;
      Pb8[prow * 40 + lrow] = (u8)pk;
      Pb8[prow * 40 + 16 + lrow] = (u8)(pk >> 8);
    }

    __syncthreads();  // P visible; Ks fully consumed

    const int kknext = (it + 1) * 32;
    if (it < ITERS - 1) {    // prefetch K(it+1), flies during PV
#pragma unroll
      for (int i = 0; i < 4; i++) {
        int row = w * 8 + i * 2 + (lane >> 5);
        int g = (lane & 31) ^ (row & 7);
        gload_lds16(&K[(keybase + kknext + row) * 512 + g * 16],
                    &Ks8[(w * 8 + i * 2) * 512]);
      }
    }

    // ---- PV (fp8): hoist all fragment reads, drain, prefetch V, MFMA ----
    i64 af[2][2];
#pragma unroll
    for (int i = 0; i < 2; i++)
#pragma unroll
      for (int kg = 0; kg < 2; kg++)
        af[i][kg] = *(const i64*)&Pb8[(i * 32 + l31) * 40 + kg * 16 + half * 8];

    i64 bv[4][2];
#pragma unroll
    for (int j = 0; j < 4; j++) {
      int n = w * 128 + j * 32 + l31;
      int x = (n >> 2) & 1;
#pragma unroll
      for (int kg = 0; kg < 2; kg++)
        bv[j][kg] = *(const i64*)&Vs8[n * 32 + (kg ^ x) * 16 + half * 8];
    }

    asm volatile("s_waitcnt lgkmcnt(0)" ::: "memory");

    if (it < ITERS - 1) {    // prefetch V(it+1), wave-private slice
#pragma unroll
      for (int run = 0; run < 4; run++) {
        int rowb = w * 128 + run * 32;
        int n = rowb + (lane >> 1);
        int g16 = (lane & 1) ^ ((n >> 2) & 1);
        gload_lds16(&Vt8[n * 16384 + keybase + kknext + g16 * 16], &Vs8[rowb * 32]);
      }
    }

    __builtin_amdgcn_s_setprio(1);
#pragma unroll
    for (int j = 0; j < 4; j++)
#pragma unroll
      for (int i = 0; i < 2; i++) {
        Oacc[i][j] = __builtin_amdgcn_mfma_f32_32x32x16_fp8_fp8(af[i][0], bv[j][0], Oacc[i][j], 0, 0, 0);
        Oacc[i][j] = __builtin_amdgcn_mfma_f32_32x32x16_fp8_fp8(af[i][1], bv[j][1], Oacc[i][j], 0, 0, 0);
      }
    __builtin_amdgcn_s_setprio(0);
  }

  // ---- reduce l across the 16 key-lanes ----
#pragma unroll
  for (int r = 0; r < 4; r++) {
    float s = lsum[r];
    s += __shfl_xor(s, 1); s += __shfl_xor(s, 2);
    s += __shfl_xor(s, 4); s += __shfl_xor(s, 8);
    lsum[r] = s;
  }
  const int tokw = b * 4096 + q0 + w * 16 + quad * 4;
  if (lrow == 0) {
#pragma unroll
    for (int r = 0; r < 4; r++)
      L[split * 16384 + tokw + r] = lsum[r];
  }

  // ---- store unnormalized O partial, bf16 (32x32 C-layout) ----
  u16* Ob = Opart + (size_t)split * (16384u * 512u);
  const int tokbase = b * 4096 + q0;
#pragma unroll
  for (int i = 0; i < 2; i++)
#pragma unroll
    for (int j = 0; j < 4; j++) {
      int col = w * 128 + j * 32 + l31;
#pragma unroll
      for (int p = 0; p < 16; p++) {
        int row = i * 32 + (p & 3) + 8 * (p >> 2) + 4 * half;
        Ob[(tokbase + row) * 512 + col] = f2bf(Oacc[i][j][p]);
      }
    }
}

// ---------------------------------------------------------------------------
// Kernel 4: combine splits + residual + LayerNorm.  One wave per token.
// ---------------------------------------------------------------------------
template <int NSPLIT>
__launch_bounds__(256)
__global__ void combine_ln_kernel(const u16* __restrict__ Opart,
                                  const float* __restrict__ L,
                                  const float* __restrict__ X,
                                  const float* __restrict__ gamma,
                                  const float* __restrict__ beta,
                                  float* __restrict__ Out) {
  const int lane = threadIdx.x & 63;
  const int tok = blockIdx.x * 4 + (threadIdx.x >> 6);
  float lt = 0.f;
#pragma unroll
  for (int s = 0; s < NSPLIT; s++) lt += L[s * 16384 + tok];
  const float inv_l = 1.f / lt;
  const int base = tok * 512 + lane * 8;

  float h[8] = {0.f, 0.f, 0.f, 0.f, 0.f, 0.f, 0.f, 0.f};
#pragma unroll
  for (int s = 0; s < NSPLIT; s++) {
    uint4 avec = *(const uint4*)&Opart[(size_t)s * (16384u * 512u) + base];
    const u16* ap = (const u16*)&avec;
#pragma unroll
    for (int i = 0; i < 8; i++) h[i] += bf2f(ap[i]);
  }

  float4 x0 = *(const float4*)&X[base];
  float4 x1 = *(const float4*)&X[base + 4];
  float xs[8] = {x0.x, x0.y, x0.z, x0.w, x1.x, x1.y, x1.z, x1.w};
#pragma unroll
  for (int i = 0; i < 8; i++) h[i] = h[i] * inv_l + xs[i];

  float sum = 0.f, sq = 0.f;
#pragma unroll
  for (int i = 0; i < 8; i++) { sum += h[i]; sq += h[i] * h[i]; }
#pragma unroll
  for (int d = 1; d < 64; d <<= 1) {
    sum += __shfl_xor(sum, d);
    sq  += __shfl_xor(sq, d);
  }
  float mu = sum * (1.f / 512.f);
  float var = sq * (1.f / 512.f) - mu * mu;
  float rstd = rsqrtf(var + LN_EPS);

  float4 g0 = *(const float4*)&gamma[lane * 8];
  float4 g1 = *(const float4*)&gamma[lane * 8 + 4];
  float4 b0 = *(const float4*)&beta[lane * 8];
  float4 b1 = *(const float4*)&beta[lane * 8 + 4];
  float gs[8] = {g0.x, g0.y, g0.z, g0.w, g1.x, g1.y, g1.z, g1.w};
  float bs[8] = {b0.x, b0.y, b0.z, b0.w, b1.x, b1.y, b1.z, b1.w};

  float4 o0, o1;
  float* op = (float*)&o0;
#pragma unroll
  for (int i = 0; i < 4; i++) op[i] = (h[i] - mu) * rstd * gs[i] + bs[i];
  float* op1 = (float*)&o1;
#pragma unroll
  for (int i = 0; i < 4; i++) op1[i] = (h[i + 4] - mu) * rstd * gs[i + 4] + bs[i + 4];
  *(float4*)&Out[base] = o0;
  *(float4*)&Out[base + 4] = o1;
}

// ---------------------------------------------------------------------------
extern "C" void kernel_launch(void* const* d_in, const int* in_sizes, int n_in,
                              void* d_out, int out_size, void* d_ws, size_t ws_size,
                              hipStream_t stream) {
  const float* x = (const float*)d_in[0];
  const float* Wq = (const float*)d_in[1];
  const float* Wk = (const float*)d_in[2];
  const float* Wv = (const float*)d_in[3];
  const float* gamma = (const float*)d_in[4];
  const float* beta = (const float*)d_in[5];

  char* ws = (char*)d_ws;
  u8*  Qws   = (u8*)(ws);                     // 8 MB fp8
  u8*  Kws   = (u8*)(ws + 8388608);           // 8 MB fp8
  u8*  Vt8ws = (u8*)(ws + 16777216);          // 8 MB fp8, [512][16384]
  u16* Wtws  = (u16*)(ws + 25165824);         // 1.5 MB bf16
  u16* Xbws  = (u16*)(ws + 26738688);         // 16 MB bf16 (dead after GEMM)
  u16* Opws  = (u16*)(ws + 26738688);         // 2 x 16 MB bf16 partials;
                                              //   slice 0 aliases Xb (safe:
                                              //   attn writes after gemm reads)
  const size_t PART = 16777216;
  float* Lws = (float*)(ws + 26738688 + 2 * PART);  // [2][16384] f32

  hipLaunchKernelGGL(prep_kernel, dim3(4288), dim3(256), 0, stream,
                     x, Xbws, Wq, Wk, Wv, Wtws);
  hipLaunchKernelGGL(qkv_gemm_kernel, dim3(512, 3), dim3(256), 0, stream,
                     Xbws, Wtws, Qws, Kws, Vt8ws);
  hipLaunchKernelGGL(HIP_KERNEL_NAME(attn_partial_kernel<2>),
                     dim3(64, 4, 2), dim3(256), 0, stream,
                     Qws, Kws, Vt8ws, Opws, Lws);
  hipLaunchKernelGGL(HIP_KERNEL_NAME(combine_ln_kernel<2>),
                     dim3(4096), dim3(256), 0, stream,
                     Opws, Lws, x, gamma, beta, (float*)d_out);
}

// Round 12
// 267.292 us; speedup vs baseline: 2.0118x; 1.0146x over previous
//
#include <hip/hip_runtime.h>
#include <stdint.h>

typedef __attribute__((ext_vector_type(8))) __bf16 bf16x8;
typedef __attribute__((ext_vector_type(4))) float f32x4;
typedef __attribute__((ext_vector_type(16))) float f32x16;
typedef unsigned short u16;
typedef unsigned char u8;
typedef unsigned int u32;
typedef unsigned long long u64;
typedef long i64;

#define LN_EPS 1e-5f

__device__ __forceinline__ float bf2f(u16 u){
  union { u32 i; float f; } v; v.i = ((u32)u) << 16; return v.f;
}
__device__ __forceinline__ u16 f2bf(float f){
  union { float f; u32 i; } v; v.f = f;
  u32 u = v.i;
  u += 0x7fffu + ((u >> 16) & 1u);
  return (u16)(u >> 16);
}
// HW packed f32x2 -> 2x OCP e4m3 bytes (low word of dst). RNE + sat@448.
__device__ __forceinline__ u32 cvt_pk_fp8(float a, float b){
  u32 pk;
  asm("v_cvt_pk_fp8_f32 %0, %1, %2" : "=v"(pk) : "v"(a), "v"(b));
  return pk;   // byte0 = fp8(a), byte1 = fp8(b)
}

// Async global->LDS DMA, 16 B per lane (dest = uniform base + lane*16).
__device__ __forceinline__ void gload_lds16(const void* g, void* l) {
  __builtin_amdgcn_global_load_lds(
      (const __attribute__((address_space(1))) void*)g,
      (__attribute__((address_space(3))) void*)l, 16, 0, 0);
}

// ---------------------------------------------------------------------------
// Kernel 0 (merged): blocks 0..4095 cast X f32->bf16; blocks 4096..4287
// transpose the three 512x512 weight matrices via 64x64 LDS tiles.
// (r8/r10-verified; fixes transpose_w's 16x read amplification, saves ~8 us.)
// ---------------------------------------------------------------------------
__global__ void prep_kernel(const float* __restrict__ X, u16* __restrict__ Xb,
                            const float* __restrict__ Wq,
                            const float* __restrict__ Wk,
                            const float* __restrict__ Wv,
                            u16* __restrict__ Wt) {
  __shared__ float Ts[64 * 65];   // stride 65 dwords: conflict-free both ways
  const int tid = threadIdx.x;
  const int bid = blockIdx.x;
  if (bid < 4096) {
    int idx = (bid * 256 + tid) * 8;
    float4 f0 = *(const float4*)&X[idx];
    float4 f1 = *(const float4*)&X[idx + 4];
    ushort4 lo, hi;
    lo.x = f2bf(f0.x); lo.y = f2bf(f0.y); lo.z = f2bf(f0.z); lo.w = f2bf(f0.w);
    hi.x = f2bf(f1.x); hi.y = f2bf(f1.y); hi.z = f2bf(f1.z); hi.w = f2bf(f1.w);
    *(ushort4*)&Xb[idx] = lo;
    *(ushort4*)&Xb[idx + 4] = hi;
    return;
  }
  const int t = bid - 4096;            // 0..191
  const int m = t >> 6;                // matrix index
  const int tt = t & 63;               // 8x8 grid of 64x64 tiles
  const int d0 = (tt >> 3) * 64, e0 = (tt & 7) * 64;
  const float* W = (m == 0) ? Wq : ((m == 1) ? Wk : Wv);
  u16* o = Wt + m * 512 * 512;

  const int r4 = tid >> 6;             // wave id: 4 rows per pass
  const int c = tid & 63;
#pragma unroll
  for (int rr = 0; rr < 16; rr++) {
    int r = rr * 4 + r4;
    Ts[c * 65 + r] = W[(d0 + r) * 512 + e0 + c];   // coalesced read
  }
  __syncthreads();
#pragma unroll
  for (int it = 0; it < 2; it++) {
    int task = it * 256 + tid;
    int e = task >> 3;
    int seg = task & 7;
    const float* src = &Ts[e * 65 + seg * 8];
    union { u16 h[8]; uint4 v; } pk;
#pragma unroll
    for (int j = 0; j < 8; j++) pk.h[j] = f2bf(src[j]);
    *(uint4*)&o[(e0 + e) * 512 + d0 + seg * 8] = pk.v;   // coalesced write
  }
}

// ---------------------------------------------------------------------------
// Kernel 2: QKV GEMM — exact r7 version (harness-proven at r6/r7/r10).
// Q/K byte-store epilogue, V via LDS transpose tile + coalesced row stores.
// ---------------------------------------------------------------------------
__launch_bounds__(256, 4)
__global__ void qkv_gemm_kernel(const u16* __restrict__ Xb,
                                const u16* __restrict__ Wt,
                                u8* __restrict__ Qo,
                                u8* __restrict__ Ko,
                                u8* __restrict__ Vto8) {
  const int z = blockIdx.y;
  const u16* Wtm = Wt + z * 512 * 512;
  const int mblk = blockIdx.x & 127;
  const int nblk = blockIdx.x >> 7;
  const int m0 = mblk * 128, n0 = nblk * 128;

  __shared__ __align__(16) u8 As[128 * 64];   // 8 KB
  __shared__ __align__(16) u8 Bs[128 * 64];   // 8 KB
  __shared__ __align__(16) u8 Ls[128 * 144];  // 18 KB, V epilogue transpose

  const int tid = threadIdx.x;
  const int lane = tid & 63, w = tid >> 6;
  const int wr = w >> 1, wc = w & 1;
  const int lrow = lane & 15, quad = lane >> 4;

  f32x4 acc[4][4];
#pragma unroll
  for (int i = 0; i < 4; i++)
#pragma unroll
    for (int j = 0; j < 4; j++) acc[i][j] = (f32x4){0.f, 0.f, 0.f, 0.f};

  const int srow = lane >> 2;          // 0..15 within run
  const int spos = lane & 3;           // granule position 0..3

  // preload k0 = 0
#pragma unroll
  for (int r2 = 0; r2 < 2; r2++) {
    int rowb = w * 32 + r2 * 16;
    int row = rowb + srow;
    int g = spos ^ (row & 3);
    gload_lds16(&Xb[(m0 + row) * 512 + g * 8], &As[rowb * 64]);
    gload_lds16(&Wtm[(n0 + row) * 512 + g * 8], &Bs[rowb * 64]);
  }

  for (int k = 0; k < 16; k++) {
    __syncthreads();   // tile-k DMAs complete (implicit vmcnt(0))
    bf16x8 a[4], b[4];
#pragma unroll
    for (int t = 0; t < 4; t++) {
      int ra = wr * 64 + t * 16 + lrow;
      a[t] = *(const bf16x8*)&As[ra * 64 + (quad ^ (ra & 3)) * 16];
      int rb = wc * 64 + t * 16 + lrow;
      b[t] = *(const bf16x8*)&Bs[rb * 64 + (quad ^ (rb & 3)) * 16];
    }
    __syncthreads();   // all waves' fragment reads done -> safe to restage
    if (k < 15) {
      int k0n = (k + 1) * 32;
#pragma unroll
      for (int r2 = 0; r2 < 2; r2++) {
        int rowb = w * 32 + r2 * 16;
        int row = rowb + srow;
        int g = spos ^ (row & 3);
        gload_lds16(&Xb[(m0 + row) * 512 + k0n + g * 8], &As[rowb * 64]);
        gload_lds16(&Wtm[(n0 + row) * 512 + k0n + g * 8], &Bs[rowb * 64]);
      }
    }
#pragma unroll
    for (int i = 0; i < 4; i++)
#pragma unroll
      for (int j = 0; j < 4; j++)
        acc[i][j] = __builtin_amdgcn_mfma_f32_16x16x32_bf16(a[i], b[j], acc[i][j], 0, 0, 0);
  }

  if (z < 2) {
    u8* O = (z == 0) ? Qo : Ko;
#pragma unroll
    for (int i = 0; i < 4; i++) {
      int rbase = m0 + wr * 64 + i * 16 + quad * 4;
#pragma unroll
      for (int j = 0; j < 4; j++) {
        int col = n0 + wc * 64 + j * 16 + lrow;
        u32 pk01 = cvt_pk_fp8(acc[i][j][0], acc[i][j][1]);
        u32 pk23 = cvt_pk_fp8(acc[i][j][2], acc[i][j][3]);
        O[(rbase + 0) * 512 + col] = (u8)pk01;
        O[(rbase + 1) * 512 + col] = (u8)(pk01 >> 8);
        O[(rbase + 2) * 512 + col] = (u8)pk23;
        O[(rbase + 3) * 512 + col] = (u8)(pk23 >> 8);
      }
    }
  } else {
    // ---- V: LDS transpose tile, then coalesced row stores (r6 path) ----
#pragma unroll
    for (int i = 0; i < 4; i++) {
      int tokb = wr * 64 + i * 16 + quad * 4;
#pragma unroll
      for (int j = 0; j < 4; j++) {
        int el = wc * 64 + j * 16 + lrow;
        u32 pk01 = cvt_pk_fp8(acc[i][j][0], acc[i][j][1]);
        u32 pk23 = cvt_pk_fp8(acc[i][j][2], acc[i][j][3]);
        u32 pk = (pk01 & 0xffffu) | (pk23 << 16);
        *(u32*)&Ls[el * 144 + tokb] = pk;
      }
    }
    __syncthreads();
#pragma unroll
    for (int k = 0; k < 4; k++) {
      int e = w * 32 + k * 8 + (lane >> 3);
      int tok = (lane & 7) * 16;
      uint4 vv = *(const uint4*)&Ls[e * 144 + tok];
      *(uint4*)&Vto8[(size_t)(n0 + e) * 16384 + m0 + tok] = vv;
    }
  }
}

// ---------------------------------------------------------------------------
// Kernel 3: flash attention partial, all-fp8 MFMA paths.
// EXACT r6 schedule (measured 148 us).  r10 A/B: adding s_setprio cost
// +10.5 us (158.5) — dropped per pre-commitment.  No setprio, no dbuf:
// this barrier schedule with cross-block phase overlap is the best measured
// across 7 structural variants (r0/r1/r4/r5/r6/r7/r10).
// ---------------------------------------------------------------------------
template <int NSPLIT>
__launch_bounds__(256, 2)
__global__ void attn_partial_kernel(const u8* __restrict__ Q,
                                    const u8* __restrict__ K,
                                    const u8* __restrict__ Vt8,
                                    u16* __restrict__ Opart,  // [NSPLIT][16384][512]
                                    float* __restrict__ L) {  // [NSPLIT][16384]
  constexpr int SPAN = 4096 / NSPLIT;   // keys per split
  constexpr int ITERS = SPAN / 32;      // 32-key tiles
  const int b = blockIdx.y;
  const int split = blockIdx.z;
  const int q0 = blockIdx.x * 64;
  const int tid = threadIdx.x;
  const int lane = tid & 63, w = tid >> 6;
  const int lrow = lane & 15, quad = lane >> 4;
  const int l31 = lane & 31, half = lane >> 5;

  __shared__ __align__(16) u8 Ks8[32 * 512];   // fp8, 16B-granule swizzle g^(row&7)
  __shared__ __align__(16) u8 Vs8[512 * 32];   // fp8, granule g16^((n>>2)&1)
  __shared__ __align__(16) u8 Pb8[64 * 40];    // fp8 P, row stride 40 B

  const int keybase = b * 4096 + split * SPAN;

  const int qtok = b * 4096 + q0 + w * 16 + lrow;
  i64 qf[16];
#pragma unroll
  for (int s = 0; s < 16; s++)
    qf[s] = *(const i64*)&Q[qtok * 512 + s * 32 + quad * 8];

  f32x16 Oacc[2][4];
#pragma unroll
  for (int i = 0; i < 2; i++)
#pragma unroll
    for (int j = 0; j < 4; j++)
#pragma unroll
      for (int e = 0; e < 16; e++) Oacc[i][j][e] = 0.f;

  float lsum[4] = {0.f, 0.f, 0.f, 0.f};
  const float scale = 0.044194173824159216f;  // 1/sqrt(512)

  // ---- preload tile 0 ----
#pragma unroll
  for (int i = 0; i < 4; i++) {       // K fp8: 8 rows/wave, 2 rows per run
    int row = w * 8 + i * 2 + (lane >> 5);
    int g = (lane & 31) ^ (row & 7);
    gload_lds16(&K[(keybase + row) * 512 + g * 16], &Ks8[(w * 8 + i * 2) * 512]);
  }
#pragma unroll
  for (int run = 0; run < 4; run++) { // V fp8: wave-private 128 rows, 32/run
    int rowb = w * 128 + run * 32;
    int n = rowb + (lane >> 1);
    int g16 = (lane & 1) ^ ((n >> 2) & 1);
    gload_lds16(&Vt8[n * 16384 + keybase + g16 * 16], &Vs8[rowb * 32]);
  }

  for (int it = 0; it < ITERS; ++it) {
    __syncthreads();  // tile-it DMAs done (implicit vmcnt(0)); Pb8(it-1) free

    // ---- QK^T (fp8) : S[16 rows][32 keys] per wave ----
    f32x4 S0 = {0.f, 0.f, 0.f, 0.f}, S1 = {0.f, 0.f, 0.f, 0.f};
#pragma unroll
    for (int s = 0; s < 16; s++) {
      int gs = (2 * s + (quad >> 1)) ^ (lrow & 7);
      int off = gs * 16 + (quad & 1) * 8;
      i64 k0 = *(const i64*)&Ks8[lrow * 512 + off];
      i64 k1 = *(const i64*)&Ks8[(16 + lrow) * 512 + off];
      S0 = __builtin_amdgcn_mfma_f32_16x16x32_fp8_fp8(qf[s], k0, S0, 0, 0, 0);
      S1 = __builtin_amdgcn_mfma_f32_16x16x32_fp8_fp8(qf[s], k1, S1, 0, 0, 0);
    }

    // ---- fixed-max softmax + write P as fp8 (HW packed convert) ----
#pragma unroll
    for (int r = 0; r < 4; r++) {
      float p0 = __expf(S0[r] * scale);
      float p1 = __expf(S1[r] * scale);
      lsum[r] += p0 + p1;
      u32 pk = cvt_pk_fp8(p0, p1);
      int prow = w * 16 + quad * 4 + r;
      Pb8[prow * 40 + lrow] = (u8)pk;
      Pb8[prow * 40 + 16 + lrow] = (u8)(pk >> 8);
    }

    __syncthreads();  // P visible; Ks fully consumed

    const int kknext = (it + 1) * 32;
    if (it < ITERS - 1) {    // prefetch K(it+1), flies during PV
#pragma unroll
      for (int i = 0; i < 4; i++) {
        int row = w * 8 + i * 2 + (lane >> 5);
        int g = (lane & 31) ^ (row & 7);
        gload_lds16(&K[(keybase + kknext + row) * 512 + g * 16],
                    &Ks8[(w * 8 + i * 2) * 512]);
      }
    }

    // ---- PV (fp8): hoist all fragment reads, drain, prefetch V, MFMA ----
    i64 af[2][2];
#pragma unroll
    for (int i = 0; i < 2; i++)
#pragma unroll
      for (int kg = 0; kg < 2; kg++)
        af[i][kg] = *(const i64*)&Pb8[(i * 32 + l31) * 40 + kg * 16 + half * 8];

    i64 bv[4][2];
#pragma unroll
    for (int j = 0; j < 4; j++) {
      int n = w * 128 + j * 32 + l31;
      int x = (n >> 2) & 1;
#pragma unroll
      for (int kg = 0; kg < 2; kg++)
        bv[j][kg] = *(const i64*)&Vs8[n * 32 + (kg ^ x) * 16 + half * 8];
    }

    asm volatile("s_waitcnt lgkmcnt(0)" ::: "memory");

    if (it < ITERS - 1) {    // prefetch V(it+1), wave-private slice
#pragma unroll
      for (int run = 0; run < 4; run++) {
        int rowb = w * 128 + run * 32;
        int n = rowb + (lane >> 1);
        int g16 = (lane & 1) ^ ((n >> 2) & 1);
        gload_lds16(&Vt8[n * 16384 + keybase + kknext + g16 * 16], &Vs8[rowb * 32]);
      }
    }

#pragma unroll
    for (int j = 0; j < 4; j++)
#pragma unroll
      for (int i = 0; i < 2; i++) {
        Oacc[i][j] = __builtin_amdgcn_mfma_f32_32x32x16_fp8_fp8(af[i][0], bv[j][0], Oacc[i][j], 0, 0, 0);
        Oacc[i][j] = __builtin_amdgcn_mfma_f32_32x32x16_fp8_fp8(af[i][1], bv[j][1], Oacc[i][j], 0, 0, 0);
      }
  }

  // ---- reduce l across the 16 key-lanes ----
#pragma unroll
  for (int r = 0; r < 4; r++) {
    float s = lsum[r];
    s += __shfl_xor(s, 1); s += __shfl_xor(s, 2);
    s += __shfl_xor(s, 4); s += __shfl_xor(s, 8);
    lsum[r] = s;
  }
  const int tokw = b * 4096 + q0 + w * 16 + quad * 4;
  if (lrow == 0) {
#pragma unroll
    for (int r = 0; r < 4; r++)
      L[split * 16384 + tokw + r] = lsum[r];
  }

  // ---- store unnormalized O partial, bf16 (32x32 C-layout) ----
  u16* Ob = Opart + (size_t)split * (16384u * 512u);
  const int tokbase = b * 4096 + q0;
#pragma unroll
  for (int i = 0; i < 2; i++)
#pragma unroll
    for (int j = 0; j < 4; j++) {
      int col = w * 128 + j * 32 + l31;
#pragma unroll
      for (int p = 0; p < 16; p++) {
        int row = i * 32 + (p & 3) + 8 * (p >> 2) + 4 * half;
        Ob[(tokbase + row) * 512 + col] = f2bf(Oacc[i][j][p]);
      }
    }
}

// ---------------------------------------------------------------------------
// Kernel 4: combine splits + residual + LayerNorm.  One wave per token.
// ---------------------------------------------------------------------------
template <int NSPLIT>
__launch_bounds__(256)
__global__ void combine_ln_kernel(const u16* __restrict__ Opart,
                                  const float* __restrict__ L,
                                  const float* __restrict__ X,
                                  const float* __restrict__ gamma,
                                  const float* __restrict__ beta,
                                  float* __restrict__ Out) {
  const int lane = threadIdx.x & 63;
  const int tok = blockIdx.x * 4 + (threadIdx.x >> 6);
  float lt = 0.f;
#pragma unroll
  for (int s = 0; s < NSPLIT; s++) lt += L[s * 16384 + tok];
  const float inv_l = 1.f / lt;
  const int base = tok * 512 + lane * 8;

  float h[8] = {0.f, 0.f, 0.f, 0.f, 0.f, 0.f, 0.f, 0.f};
#pragma unroll
  for (int s = 0; s < NSPLIT; s++) {
    uint4 avec = *(const uint4*)&Opart[(size_t)s * (16384u * 512u) + base];
    const u16* ap = (const u16*)&avec;
#pragma unroll
    for (int i = 0; i < 8; i++) h[i] += bf2f(ap[i]);
  }

  float4 x0 = *(const float4*)&X[base];
  float4 x1 = *(const float4*)&X[base + 4];
  float xs[8] = {x0.x, x0.y, x0.z, x0.w, x1.x, x1.y, x1.z, x1.w};
#pragma unroll
  for (int i = 0; i < 8; i++) h[i] = h[i] * inv_l + xs[i];

  float sum = 0.f, sq = 0.f;
#pragma unroll
  for (int i = 0; i < 8; i++) { sum += h[i]; sq += h[i] * h[i]; }
#pragma unroll
  for (int d = 1; d < 64; d <<= 1) {
    sum += __shfl_xor(sum, d);
    sq  += __shfl_xor(sq, d);
  }
  float mu = sum * (1.f / 512.f);
  float var = sq * (1.f / 512.f) - mu * mu;
  float rstd = rsqrtf(var + LN_EPS);

  float4 g0 = *(const float4*)&gamma[lane * 8];
  float4 g1 = *(const float4*)&gamma[lane * 8 + 4];
  float4 b0 = *(const float4*)&beta[lane * 8];
  float4 b1 = *(const float4*)&beta[lane * 8 + 4];
  float gs[8] = {g0.x, g0.y, g0.z, g0.w, g1.x, g1.y, g1.z, g1.w};
  float bs[8] = {b0.x, b0.y, b0.z, b0.w, b1.x, b1.y, b1.z, b1.w};

  float4 o0, o1;
  float* op = (float*)&o0;
#pragma unroll
  for (int i = 0; i < 4; i++) op[i] = (h[i] - mu) * rstd * gs[i] + bs[i];
  float* op1 = (float*)&o1;
#pragma unroll
  for (int i = 0; i < 4; i++) op1[i] = (h[i + 4] - mu) * rstd * gs[i + 4] + bs[i + 4];
  *(float4*)&Out[base] = o0;
  *(float4*)&Out[base + 4] = o1;
}

// ---------------------------------------------------------------------------
extern "C" void kernel_launch(void* const* d_in, const int* in_sizes, int n_in,
                              void* d_out, int out_size, void* d_ws, size_t ws_size,
                              hipStream_t stream) {
  const float* x = (const float*)d_in[0];
  const float* Wq = (const float*)d_in[1];
  const float* Wk = (const float*)d_in[2];
  const float* Wv = (const float*)d_in[3];
  const float* gamma = (const float*)d_in[4];
  const float* beta = (const float*)d_in[5];

  char* ws = (char*)d_ws;
  u8*  Qws   = (u8*)(ws);                     // 8 MB fp8
  u8*  Kws   = (u8*)(ws + 8388608);           // 8 MB fp8
  u8*  Vt8ws = (u8*)(ws + 16777216);          // 8 MB fp8, [512][16384]
  u16* Wtws  = (u16*)(ws + 25165824);         // 1.5 MB bf16
  u16* Xbws  = (u16*)(ws + 26738688);         // 16 MB bf16 (dead after GEMM)
  u16* Opws  = (u16*)(ws + 26738688);         // 2 x 16 MB bf16 partials;
                                              //   slice 0 aliases Xb (safe:
                                              //   attn writes after gemm reads)
  const size_t PART = 16777216;
  float* Lws = (float*)(ws + 26738688 + 2 * PART);  // [2][16384] f32

  hipLaunchKernelGGL(prep_kernel, dim3(4288), dim3(256), 0, stream,
                     x, Xbws, Wq, Wk, Wv, Wtws);
  hipLaunchKernelGGL(qkv_gemm_kernel, dim3(512, 3), dim3(256), 0, stream,
                     Xbws, Wtws, Qws, Kws, Vt8ws);
  hipLaunchKernelGGL(HIP_KERNEL_NAME(attn_partial_kernel<2>),
                     dim3(64, 4, 2), dim3(256), 0, stream,
                     Qws, Kws, Vt8ws, Opws, Lws);
  hipLaunchKernelGGL(HIP_KERNEL_NAME(combine_ln_kernel<2>),
                     dim3(4096), dim3(256), 0, stream,
                     Opws, Lws, x, gamma, beta, (float*)d_out);
}